// Round 1
// baseline (12008.157 us; speedup 1.0000x reference)
//
#include <hip/hip_runtime.h>
#include <math.h>

#define B_DIM 64
#define T_DIM 128
#define V_DIM 10000
#define E_DIM 1024
#define H_DIM 1024
#define G4    4096
#define BT    (B_DIM*T_DIM)   // 8192

// ---------------- lengths: sum of attention mask rows ----------------
__global__ void k_lengths(const int* __restrict__ mask, int* __restrict__ len) {
  int b = threadIdx.x;
  if (b < B_DIM) {
    int s = 0;
    #pragma unroll 8
    for (int t = 0; t < T_DIM; ++t) s += mask[b*T_DIM + t];
    len[b] = s;
  }
}

// ---------------- embedding gather: x[row] = emb[ids[row]] ----------------
__global__ __launch_bounds__(256) void k_embed(const int* __restrict__ ids,
                                               const float* __restrict__ emb,
                                               float* __restrict__ x) {
  int row = blockIdx.x;
  int id = ids[row];
  const float4* src = reinterpret_cast<const float4*>(emb + (size_t)id*E_DIM);
  float4* dst = reinterpret_cast<float4*>(x + (size_t)row*E_DIM);
  dst[threadIdx.x] = src[threadIdx.x];   // 256 threads * float4 = 1024 floats
}

// ---------------- bias sum: o = a + b (4096) ----------------
__global__ void k_bias(const float* __restrict__ a, const float* __restrict__ b,
                       float* __restrict__ o) {
  int i = blockIdx.x*256 + threadIdx.x;
  o[i] = a[i] + b[i];
}

// ---------------- fp32 GEMM: C[M,N] = A[M,K] * B[N,K]^T + bias[N] ----------------
// 128x128 tile, 256 threads, 8x8 micro-tile, BK=16. K multiple of 16, M multiple of 128.
template<bool GUARD_N>
__global__ __launch_bounds__(256) void k_gemm_bt(const float* __restrict__ A,
                                                 const float* __restrict__ Bm,
                                                 const float* __restrict__ bias,
                                                 float* __restrict__ C,
                                                 int M, int N, int K) {
  __shared__ float As[16][128];
  __shared__ float Bs[16][128];
  const int tid = threadIdx.x;
  const int tx = tid & 15, ty = tid >> 4;
  const int m0 = blockIdx.y * 128;
  const int n0 = blockIdx.x * 128;
  float acc[8][8];
  #pragma unroll
  for (int i = 0; i < 8; ++i)
    #pragma unroll
    for (int j = 0; j < 8; ++j) acc[i][j] = 0.f;

  for (int k0 = 0; k0 < K; k0 += 16) {
    __syncthreads();
    #pragma unroll
    for (int it = 0; it < 2; ++it) {   // stage A tile (128 rows x 16 k), transposed
      int flat = it*256 + tid;
      int r = flat >> 2, c4 = (flat & 3)*4;
      float4 v = *reinterpret_cast<const float4*>(A + (size_t)(m0+r)*K + k0 + c4);
      As[c4+0][r] = v.x; As[c4+1][r] = v.y; As[c4+2][r] = v.z; As[c4+3][r] = v.w;
    }
    #pragma unroll
    for (int it = 0; it < 2; ++it) {   // stage B tile
      int flat = it*256 + tid;
      int r = flat >> 2, c4 = (flat & 3)*4;
      float4 v = make_float4(0.f,0.f,0.f,0.f);
      if (!GUARD_N || (n0 + r) < N)
        v = *reinterpret_cast<const float4*>(Bm + (size_t)(n0+r)*K + k0 + c4);
      Bs[c4+0][r] = v.x; Bs[c4+1][r] = v.y; Bs[c4+2][r] = v.z; Bs[c4+3][r] = v.w;
    }
    __syncthreads();
    #pragma unroll
    for (int k = 0; k < 16; ++k) {
      float a[8], b[8];
      *reinterpret_cast<float4*>(&a[0]) = *reinterpret_cast<float4*>(&As[k][ty*8]);
      *reinterpret_cast<float4*>(&a[4]) = *reinterpret_cast<float4*>(&As[k][ty*8+4]);
      *reinterpret_cast<float4*>(&b[0]) = *reinterpret_cast<float4*>(&Bs[k][tx*8]);
      *reinterpret_cast<float4*>(&b[4]) = *reinterpret_cast<float4*>(&Bs[k][tx*8+4]);
      #pragma unroll
      for (int i = 0; i < 8; ++i)
        #pragma unroll
        for (int j = 0; j < 8; ++j)
          acc[i][j] += a[i]*b[j];
    }
  }
  #pragma unroll
  for (int i = 0; i < 8; ++i) {
    int m = m0 + ty*8 + i;
    #pragma unroll
    for (int jq = 0; jq < 2; ++jq) {
      int n = n0 + tx*8 + jq*4;
      if (GUARD_N && n >= N) continue;   // N%4==0, so float4 fully in or out
      float4 v;
      v.x = acc[i][jq*4+0] + bias[n+0];
      v.y = acc[i][jq*4+1] + bias[n+1];
      v.z = acc[i][jq*4+2] + bias[n+2];
      v.w = acc[i][jq*4+3] + bias[n+3];
      *reinterpret_cast<float4*>(C + (size_t)m*N + n) = v;
    }
  }
}

// ---------------- fused LSTM step: gates = gx_t + h@Wh^T, then state update --------
// Block: 16 batches x 16 h-cols x 4 gates (1024 outputs, 4/thread).
// Grid: (B/16=4, H/16=64) = 256 blocks. h double-buffered across launches.
__global__ __launch_bounds__(256) void k_lstm_step(
    const float* __restrict__ gx, const float* __restrict__ Wh,
    const float* __restrict__ h_in, float* __restrict__ h_out,
    float* __restrict__ c, float* __restrict__ xout,
    const int* __restrict__ len, int t)
{
  __shared__ float Hs[16][H_DIM + 4];   // +4 pad: bb-strided f4 reads 2-way max
  __shared__ float Ws[64][64];          // XOR-swizzled k-chunk of Wh (row q = col*4+gate)
  const int tid = threadIdx.x;
  const int bb = tid & 15;
  const int rr = tid >> 4;              // 0..15 -> h-col
  const int b0 = blockIdx.x * 16;
  const int j0 = blockIdx.y * 16;

  #pragma unroll
  for (int i = 0; i < 16; ++i)
    *reinterpret_cast<float4*>(&Hs[i][tid*4]) =
      *reinterpret_cast<const float4*>(&h_in[(size_t)(b0+i)*H_DIM + tid*4]);

  float acc0 = 0.f, acc1 = 0.f, acc2 = 0.f, acc3 = 0.f;
  for (int kc = 0; kc < H_DIM; kc += 64) {
    __syncthreads();                    // Hs ready (iter 0) / prev compute done
    #pragma unroll
    for (int it = 0; it < 4; ++it) {    // stage 64 rows x 64 k, swizzled
      int flat = it*256 + tid;
      int q = flat >> 4;                // 0..63 : gate = q&3, col = q>>2
      int c4 = flat & 15;
      int wrow = (q & 3)*H_DIM + j0 + (q >> 2);
      float4 v = *reinterpret_cast<const float4*>(&Wh[(size_t)wrow*H_DIM + kc + c4*4]);
      *reinterpret_cast<float4*>(&Ws[q][(c4 ^ (q & 7))*4]) = v;
    }
    __syncthreads();
    #pragma unroll
    for (int kk = 0; kk < 64; kk += 4) {
      float4 hv = *reinterpret_cast<float4*>(&Hs[bb][kc + kk]);
      int c4 = kk >> 2;
      float4 w0 = *reinterpret_cast<float4*>(&Ws[rr*4+0][(c4 ^ ((rr*4+0) & 7))*4]);
      float4 w1 = *reinterpret_cast<float4*>(&Ws[rr*4+1][(c4 ^ ((rr*4+1) & 7))*4]);
      float4 w2 = *reinterpret_cast<float4*>(&Ws[rr*4+2][(c4 ^ ((rr*4+2) & 7))*4]);
      float4 w3 = *reinterpret_cast<float4*>(&Ws[rr*4+3][(c4 ^ ((rr*4+3) & 7))*4]);
      acc0 += hv.x*w0.x + hv.y*w0.y + hv.z*w0.z + hv.w*w0.w;
      acc1 += hv.x*w1.x + hv.y*w1.y + hv.z*w1.z + hv.w*w1.w;
      acc2 += hv.x*w2.x + hv.y*w2.y + hv.z*w2.z + hv.w*w2.w;
      acc3 += hv.x*w3.x + hv.y*w3.y + hv.z*w3.z + hv.w*w3.w;
    }
  }

  const int b = b0 + bb;
  const int j = j0 + rr;
  const size_t gbase = ((size_t)b*T_DIM + t)*G4 + j;
  float gi = acc0 + gx[gbase + 0*H_DIM];
  float gf = acc1 + gx[gbase + 1*H_DIM];
  float gg = acc2 + gx[gbase + 2*H_DIM];
  float go = acc3 + gx[gbase + 3*H_DIM];
  float si = 1.f/(1.f + expf(-gi));
  float sf = 1.f/(1.f + expf(-gf));
  float sg = tanhf(gg);
  float so = 1.f/(1.f + expf(-go));
  float c_old = c[(size_t)b*H_DIM + j];
  float c_new = sf*c_old + si*sg;
  float h_new = so * tanhf(c_new);
  bool m = t < len[b];
  float h_old = Hs[bb][j];
  h_out[(size_t)b*H_DIM + j] = m ? h_new : h_old;
  c[(size_t)b*H_DIM + j]     = m ? c_new : c_old;
  xout[((size_t)b*T_DIM + t)*H_DIM + j] = m ? h_new : 0.f;   // pad_packed zero-fill
}

// ---------------- copy final h,c into d_out tail ----------------
__global__ __launch_bounds__(256) void k_copy_state(const float* __restrict__ h,
    const float* __restrict__ c, float* __restrict__ out, int l) {
  int i = blockIdx.x*256 + threadIdx.x;  // float4 index, 16384 total
  const float4* h4 = reinterpret_cast<const float4*>(h);
  const float4* c4 = reinterpret_cast<const float4*>(c);
  float4* oh = reinterpret_cast<float4*>(out + 81920000ull + (size_t)l*65536);
  float4* oc = reinterpret_cast<float4*>(out + 81920000ull + 131072ull + (size_t)l*65536);
  oh[i] = h4[i];
  oc[i] = c4[i];
}

extern "C" void kernel_launch(void* const* d_in, const int* in_sizes, int n_in,
                              void* d_out, int out_size, void* d_ws, size_t ws_size,
                              hipStream_t stream) {
  const int*   ids  = (const int*)d_in[0];
  const int*   mask = (const int*)d_in[1];
  const float* emb  = (const float*)d_in[2];
  const float* W_ih = (const float*)d_in[3];
  const float* W_hh = (const float*)d_in[4];
  const float* b_ih = (const float*)d_in[5];
  const float* b_hh = (const float*)d_in[6];
  const float* fc_w = (const float*)d_in[7];
  const float* fc_b = (const float*)d_in[8];
  float* out = (float*)d_out;
  float* ws  = (float*)d_ws;

  // workspace layout (floats); total ~168.6 MB
  float* x    = ws;                 // [8192][1024]  layer input, overwritten by layer output
  float* gx   = ws + 8388608;       // [8192][4096]  precomputed input projection
  float* h0   = ws + 41943040;      // [64][1024] ping
  float* h1   = ws + 42008576;      // [64][1024] pong
  float* cbuf = ws + 42074112;      // [64][1024]
  float* bias = ws + 42139648;      // [4096] combined b_ih+b_hh
  int*   len  = (int*)(ws + 42143744);

  k_lengths<<<1, 64, 0, stream>>>(mask, len);
  k_embed<<<BT, 256, 0, stream>>>(ids, emb, x);

  for (int l = 0; l < 2; ++l) {
    k_bias<<<16, 256, 0, stream>>>(b_ih + l*G4, b_hh + l*G4, bias);
    k_gemm_bt<false><<<dim3(G4/128, BT/128), 256, 0, stream>>>(
        x, W_ih + (size_t)l*G4*E_DIM, bias, gx, BT, G4, E_DIM);
    hipMemsetAsync(h0, 0, (size_t)3*65536*sizeof(float), stream);  // h0,h1,c contiguous
    for (int t = 0; t < T_DIM; ++t) {
      float* hin  = (t & 1) ? h1 : h0;
      float* hout = (t & 1) ? h0 : h1;
      k_lstm_step<<<dim3(B_DIM/16, H_DIM/16), 256, 0, stream>>>(
          gx, W_hh + (size_t)l*G4*H_DIM, hin, hout, cbuf, x, len, t);
    }
    // after t=127 (odd) final h is in h0
    k_copy_state<<<64, 256, 0, stream>>>(h0, cbuf, out, l);
  }
  k_gemm_bt<true><<<dim3((V_DIM + 127)/128, BT/128), 256, 0, stream>>>(
      x, fc_w, fc_b, out, BT, V_DIM, E_DIM);
}